// Round 1
// baseline (651.175 us; speedup 1.0000x reference)
//
#include <hip/hip_runtime.h>

#define B_TOT 16384
#define HD 256
#define ID 128
#define BT 64
#define NSTEP 8
#define YP 264   // y LDS pitch (elements): 264*2B=528B rows -> 4-bank shift per row
#define XP 136   // x LDS pitch

typedef float    f32x4 __attribute__((ext_vector_type(4)));
typedef _Float16 f16x8 __attribute__((ext_vector_type(8)));
typedef _Float16 f16x4 __attribute__((ext_vector_type(4)));
typedef _Float16 f16x2 __attribute__((ext_vector_type(2)));

__device__ __forceinline__ float fast_rcp(float x){ return __builtin_amdgcn_rcpf(x); }
__device__ __forceinline__ float fast_exp2(float x){ return __builtin_amdgcn_exp2f(x); }
// tanh(x) = 1 - 2/(1+e^{2x}) ; exact limits at +-inf, ~1ulp core
__device__ __forceinline__ float fast_tanh(float x){
  return 1.0f - 2.0f*fast_rcp(1.0f + fast_exp2(x*2.8853900817779268f));
}
__device__ __forceinline__ float fast_sigmoid(float x){
  return fast_rcp(1.0f + fast_exp2(x*-1.4426950408889634f));
}

__global__ void cvt_f32_f16(const float* __restrict__ src, _Float16* __restrict__ dst, int n4){
  int i = blockIdx.x*256 + threadIdx.x;
  if (i < n4){
    float4 v = ((const float4*)src)[i];
    f16x4 t = {(_Float16)v.x, (_Float16)v.y, (_Float16)v.z, (_Float16)v.w};
    *(f16x4*)(dst + (size_t)i*4) = t;
  }
}

#define MFMA8(AC, A0,A1,A2,A3, B0,B1) \
  AC[0][0] = __builtin_amdgcn_mfma_f32_16x16x32_f16(A0,B0,AC[0][0],0,0,0); \
  AC[1][0] = __builtin_amdgcn_mfma_f32_16x16x32_f16(A1,B0,AC[1][0],0,0,0); \
  AC[2][0] = __builtin_amdgcn_mfma_f32_16x16x32_f16(A2,B0,AC[2][0],0,0,0); \
  AC[3][0] = __builtin_amdgcn_mfma_f32_16x16x32_f16(A3,B0,AC[3][0],0,0,0); \
  AC[0][1] = __builtin_amdgcn_mfma_f32_16x16x32_f16(A0,B1,AC[0][1],0,0,0); \
  AC[1][1] = __builtin_amdgcn_mfma_f32_16x16x32_f16(A1,B1,AC[1][1],0,0,0); \
  AC[2][1] = __builtin_amdgcn_mfma_f32_16x16x32_f16(A2,B1,AC[2][1],0,0,0); \
  AC[3][1] = __builtin_amdgcn_mfma_f32_16x16x32_f16(A3,B1,AC[3][1],0,0,0);

#define ELEM_LOOP \
  _Pragma("unroll") for (int mt=0; mt<4; ++mt) \
  _Pragma("unroll") for (int ntl=0; ntl<2; ++ntl) \
  _Pragma("unroll") for (int r=0; r<4; ++r)

#define ELEM_IDX \
  const int row = mt*16 + q*4 + r; const int col = colw + ntl*16 + l16; \
  const int pk = mt*4 + ntl*2 + (r>>1); const int hw = r & 1; \
  (void)row; (void)col; (void)pk; (void)hw;

#define KP(i) ((float)kpk[i][pk][hw])

__global__ __launch_bounds__(512, 2)
void ode_lstm(const float* __restrict__ inputs, const float* __restrict__ h0,
              const float* __restrict__ c0,     const float* __restrict__ ts,
              const float* __restrict__ b_ih,   const float* __restrict__ b_hh,
              const float* __restrict__ b1,     const float* __restrict__ b2,
              const _Float16* __restrict__ W1h, const _Float16* __restrict__ W2h,
              const _Float16* __restrict__ Wihh,const _Float16* __restrict__ Whhh,
              float* __restrict__ out)
{
  __shared__ __align__(16) _Float16 yl[BT*YP];
  __shared__ __align__(16) _Float16 xl[BT*XP];
  __shared__ float dtl[BT];

  const int tid  = threadIdx.x;
  const int wv   = tid >> 6;
  const int lane = tid & 63;
  const int q    = lane >> 4;
  const int l16  = lane & 15;
  const int row0 = blockIdx.x * BT;
  const int colw = wv * 32;            // this wave's 32-column output strip

  // ---- stage x (inputs) into LDS as f16, coalesced float4 ----
  #pragma unroll
  for (int it = 0; it < 4; ++it){
    int idx = tid + it*512;            // 0..2047 = 64 rows * 32 float4
    int r  = idx >> 5, c4 = idx & 31;
    float4 v = ((const float4*)inputs)[(size_t)(row0 + r)*(ID/4) + c4];
    f16x4 t = {(_Float16)v.x, (_Float16)v.y, (_Float16)v.z, (_Float16)v.w};
    *(f16x4*)(xl + r*XP + c4*4) = t;
  }
  if (tid < BT) dtl[tid] = ts[row0 + tid] * (1.0f/NSTEP);

  float b1v[2], b2v[2];
  #pragma unroll
  for (int ntl = 0; ntl < 2; ++ntl){
    b1v[ntl] = b1[colw + ntl*16 + l16];
    b2v[ntl] = b2[colw + ntl*16 + l16];
  }

  // ---- master h (fp32, C-layout regs) + initial y = h ----
  float h[4][2][4];
  ELEM_LOOP {
    ELEM_IDX
    float v = h0[(size_t)(row0+row)*HD + col];
    h[mt][ntl][r] = v;
    yl[row*YP + col] = (_Float16)v;
  }

  // GEMM: acc[mt][ntl] += A(rows mt*16+l16, K) * W(row nbase+ntl*16+l16, K)^T
  auto gemm2 = [&](const _Float16* __restrict__ W, const int rowlen, const int nkt,
                   const _Float16* __restrict__ Asrc, const int apitch,
                   f32x4 (&acc)[4][2], const int nbase){
    #pragma unroll 2
    for (int kt = 0; kt < nkt; ++kt){
      const int ko = kt*32 + q*8;
      f16x8 B0 = *(const f16x8*)(W + (size_t)(nbase + l16     )*rowlen + ko);
      f16x8 B1 = *(const f16x8*)(W + (size_t)(nbase + 16 + l16)*rowlen + ko);
      f16x8 A0 = *(const f16x8*)(Asrc + ( 0 + l16)*apitch + ko);
      f16x8 A1 = *(const f16x8*)(Asrc + (16 + l16)*apitch + ko);
      f16x8 A2 = *(const f16x8*)(Asrc + (32 + l16)*apitch + ko);
      f16x8 A3 = *(const f16x8*)(Asrc + (48 + l16)*apitch + ko);
      MFMA8(acc, A0,A1,A2,A3, B0,B1)
    }
  };

  // f(y) = tanh(y@W1^T + b1)@W2^T + b2 ; y read from yl, result fp32 in kc
  auto f_eval = [&](f32x4 (&kc)[4][2]){
    f32x4 a1[4][2] = {};
    __syncthreads();                         // y writes visible
    gemm2(W1h, HD, 8, yl, YP, a1, colw);
    __syncthreads();                         // all A-reads of y done
    ELEM_LOOP {
      ELEM_IDX
      yl[row*YP + col] = (_Float16)fast_tanh(a1[mt][ntl][r] + b1v[ntl]);
    }
    __syncthreads();                         // u ready
    f32x4 a2[4][2] = {};
    gemm2(W2h, HD, 8, yl, YP, a2, colw);
    __syncthreads();                         // u reads done, y free to overwrite
    ELEM_LOOP {
      ELEM_IDX
      kc[mt][ntl][r] = a2[mt][ntl][r] + b2v[ntl];
    }
  };

  // ================= RK45 (Dormand-Prince) =================
  #pragma unroll 1
  for (int step = 0; step < NSTEP; ++step){
    f16x2 kpk[5][16];   // dt-scaled slopes k1..k5, f16-packed in VGPRs
    f32x4 kc[4][2];

    f_eval(kc);  // k1
    ELEM_LOOP { ELEM_IDX
      float kd = dtl[row]*kc[mt][ntl][r];
      kpk[0][pk][hw] = (_Float16)kd;
      yl[row*YP+col] = (_Float16)(h[mt][ntl][r] + 0.2f*kd);
    }
    f_eval(kc);  // k2
    ELEM_LOOP { ELEM_IDX
      float kd = dtl[row]*kc[mt][ntl][r];
      kpk[1][pk][hw] = (_Float16)kd;
      yl[row*YP+col] = (_Float16)(h[mt][ntl][r] + 0.075f*KP(0) + 0.225f*kd);
    }
    f_eval(kc);  // k3
    ELEM_LOOP { ELEM_IDX
      float kd = dtl[row]*kc[mt][ntl][r];
      kpk[2][pk][hw] = (_Float16)kd;
      yl[row*YP+col] = (_Float16)(h[mt][ntl][r] + (44.0f/45.0f)*KP(0)
                        + (-56.0f/15.0f)*KP(1) + (32.0f/9.0f)*kd);
    }
    f_eval(kc);  // k4
    ELEM_LOOP { ELEM_IDX
      float kd = dtl[row]*kc[mt][ntl][r];
      kpk[3][pk][hw] = (_Float16)kd;
      yl[row*YP+col] = (_Float16)(h[mt][ntl][r] + (19372.0f/6561.0f)*KP(0)
                        + (-25360.0f/2187.0f)*KP(1) + (64448.0f/6561.0f)*KP(2)
                        + (-212.0f/729.0f)*kd);
    }
    f_eval(kc);  // k5
    ELEM_LOOP { ELEM_IDX
      float kd = dtl[row]*kc[mt][ntl][r];
      kpk[4][pk][hw] = (_Float16)kd;
      yl[row*YP+col] = (_Float16)(h[mt][ntl][r] + (9017.0f/3168.0f)*KP(0)
                        + (-355.0f/33.0f)*KP(1) + (46732.0f/5247.0f)*KP(2)
                        + (49.0f/176.0f)*KP(3) + (-5103.0f/18656.0f)*kd);
    }
    f_eval(kc);  // k6 + solution update
    ELEM_LOOP { ELEM_IDX
      float kd = dtl[row]*kc[mt][ntl][r];
      float hn = h[mt][ntl][r] + (35.0f/384.0f)*KP(0) + (500.0f/1113.0f)*KP(2)
                 + (125.0f/192.0f)*KP(3) + (-2187.0f/6784.0f)*KP(4)
                 + (11.0f/84.0f)*kd;
      h[mt][ntl][r] = hn;
      yl[row*YP+col] = (_Float16)hn;     // stage-1 input of next step / LSTM h-in
    }
  }

  // ================= two weight-shared LSTM cells =================
  float c[4][2][4];
  ELEM_LOOP { ELEM_IDX
    c[mt][ntl][r] = c0[(size_t)(row0+row)*HD + col];
  }
  float bs[4][2];
  #pragma unroll
  for (int g=0; g<4; ++g)
  #pragma unroll
  for (int ntl=0; ntl<2; ++ntl){
    int gc = g*HD + colw + ntl*16 + l16;
    bs[g][ntl] = b_ih[gc] + b_hh[gc];
  }

  #pragma unroll 1
  for (int cell = 0; cell < 2; ++cell){
    f32x4 ag[4][4][2] = {};     // gate, mt, ntl
    __syncthreads();            // h-in (yl) ready
    // x-part: K=128
    #pragma unroll 2
    for (int kt=0; kt<4; ++kt){
      const int ko = kt*32 + q*8;
      f16x8 A0 = *(const f16x8*)(xl + ( 0 + l16)*XP + ko);
      f16x8 A1 = *(const f16x8*)(xl + (16 + l16)*XP + ko);
      f16x8 A2 = *(const f16x8*)(xl + (32 + l16)*XP + ko);
      f16x8 A3 = *(const f16x8*)(xl + (48 + l16)*XP + ko);
      #pragma unroll
      for (int g=0; g<4; ++g){
        const _Float16* wr = Wihh + (size_t)(g*HD + colw + l16)*ID + ko;
        f16x8 B0 = *(const f16x8*)(wr);
        f16x8 B1 = *(const f16x8*)(wr + (size_t)16*ID);
        MFMA8(ag[g], A0,A1,A2,A3, B0,B1)
      }
    }
    // h-part: K=256
    #pragma unroll 2
    for (int kt=0; kt<8; ++kt){
      const int ko = kt*32 + q*8;
      f16x8 A0 = *(const f16x8*)(yl + ( 0 + l16)*YP + ko);
      f16x8 A1 = *(const f16x8*)(yl + (16 + l16)*YP + ko);
      f16x8 A2 = *(const f16x8*)(yl + (32 + l16)*YP + ko);
      f16x8 A3 = *(const f16x8*)(yl + (48 + l16)*YP + ko);
      #pragma unroll
      for (int g=0; g<4; ++g){
        const _Float16* wr = Whhh + (size_t)(g*HD + colw + l16)*HD + ko;
        f16x8 B0 = *(const f16x8*)(wr);
        f16x8 B1 = *(const f16x8*)(wr + (size_t)16*HD);
        MFMA8(ag[g], A0,A1,A2,A3, B0,B1)
      }
    }
    __syncthreads();            // yl reads done
    ELEM_LOOP { ELEM_IDX
      float iv = fast_sigmoid(ag[0][mt][ntl][r] + bs[0][ntl]);
      float fv = fast_sigmoid(ag[1][mt][ntl][r] + bs[1][ntl]);
      float gv = fast_tanh   (ag[2][mt][ntl][r] + bs[2][ntl]);
      float ov = fast_sigmoid(ag[3][mt][ntl][r] + bs[3][ntl]);
      float cn = fv*c[mt][ntl][r] + iv*gv;
      c[mt][ntl][r] = cn;
      float hn = ov*fast_tanh(cn);
      if (cell == 0){
        yl[row*YP + col] = (_Float16)hn;            // h1 -> next cell
      } else {
        size_t o = (size_t)(row0+row)*HD + col;
        out[o] = hn;                                // h2
        out[(size_t)B_TOT*HD + o] = cn;             // c2
      }
    }
  }
}

extern "C" void kernel_launch(void* const* d_in, const int* in_sizes, int n_in,
                              void* d_out, int out_size, void* d_ws, size_t ws_size,
                              hipStream_t stream) {
  (void)in_sizes; (void)n_in; (void)out_size; (void)ws_size;
  const float* inputs = (const float*)d_in[0];
  const float* h0     = (const float*)d_in[1];
  const float* c0     = (const float*)d_in[2];
  const float* ts     = (const float*)d_in[3];
  const float* W_ih   = (const float*)d_in[4];
  const float* W_hh   = (const float*)d_in[5];
  const float* b_ih   = (const float*)d_in[6];
  const float* b_hh   = (const float*)d_in[7];
  const float* W1     = (const float*)d_in[8];
  const float* b1     = (const float*)d_in[9];
  const float* W2     = (const float*)d_in[10];
  const float* b2     = (const float*)d_in[11];
  float* out = (float*)d_out;

  _Float16* wsh  = (_Float16*)d_ws;
  _Float16* W1h  = wsh;             // 65536
  _Float16* W2h  = wsh + 65536;     // 65536
  _Float16* Wihh = wsh + 131072;    // 131072
  _Float16* Whhh = wsh + 262144;    // 262144  (total 1 MB)

  cvt_f32_f16<<<64,  256, 0, stream>>>(W1,   W1h,  16384);
  cvt_f32_f16<<<64,  256, 0, stream>>>(W2,   W2h,  16384);
  cvt_f32_f16<<<128, 256, 0, stream>>>(W_ih, Wihh, 32768);
  cvt_f32_f16<<<256, 256, 0, stream>>>(W_hh, Whhh, 65536);

  ode_lstm<<<256, 512, 0, stream>>>(inputs, h0, c0, ts, b_ih, b_hh, b1, b2,
                                    W1h, W2h, Wihh, Whhh, out);
}

// Round 2
// 415.379 us; speedup vs baseline: 1.5677x; 1.5677x over previous
//
#include <hip/hip_runtime.h>

#define B_TOT 16384
#define HD 256
#define ID 128
#define BT 32
#define NSTEP 8
#define YP 264   // y/u LDS pitch (f16): 132 dwords == 4 banks/row shift, balanced for b128/b64
#define XP 136

typedef float    f32x4  __attribute__((ext_vector_type(4)));
typedef float    f32x16 __attribute__((ext_vector_type(16)));
typedef _Float16 f16x8  __attribute__((ext_vector_type(8)));
typedef _Float16 f16x4  __attribute__((ext_vector_type(4)));
typedef _Float16 f16x2  __attribute__((ext_vector_type(2)));

__device__ __forceinline__ float fast_rcp(float x){ return __builtin_amdgcn_rcpf(x); }
__device__ __forceinline__ float fast_exp2(float x){ return __builtin_amdgcn_exp2f(x); }
__device__ __forceinline__ float fast_tanh(float x){
  return 1.0f - 2.0f*fast_rcp(1.0f + fast_exp2(x*2.8853900817779268f));
}
__device__ __forceinline__ float fast_sigmoid(float x){
  return fast_rcp(1.0f + fast_exp2(x*-1.4426950408889634f));
}

__global__ void cvt_f32_f16(const float* __restrict__ src, _Float16* __restrict__ dst, int n4){
  int i = blockIdx.x*256 + threadIdx.x;
  if (i < n4){
    float4 v = ((const float4*)src)[i];
    f16x4 t = {(_Float16)v.x, (_Float16)v.y, (_Float16)v.z, (_Float16)v.w};
    *(f16x4*)(dst + (size_t)i*4) = t;
  }
}

// element r of f32x16 acc: feat = 32*wv + 8*(r>>2) + 4*hh + (r&3), batch = l31
#define KP(i) ((float)kpk[i][pk][hw])

__global__ __launch_bounds__(512, 2)
void ode_lstm(const float* __restrict__ inputs, const float* __restrict__ h0,
              const float* __restrict__ c0,     const float* __restrict__ ts,
              const float* __restrict__ b_ih,   const float* __restrict__ b_hh,
              const float* __restrict__ b1,     const float* __restrict__ b2,
              const _Float16* __restrict__ W1h, const _Float16* __restrict__ W2h,
              const _Float16* __restrict__ Wihh,const _Float16* __restrict__ Whhh,
              float* __restrict__ out)
{
  __shared__ __align__(16) _Float16 yl[BT*YP];
  __shared__ __align__(16) _Float16 ul[BT*YP];
  __shared__ __align__(16) _Float16 xl[BT*XP];
  __shared__ __align__(16) float b1l[HD], b2l[HD], bsl[4*HD];
  __shared__ float dtl[BT];

  const int tid  = threadIdx.x;
  const int wv   = tid >> 6;        // 8 waves: feature strip 32*wv
  const int lane = tid & 63;
  const int l31  = lane & 31;       // batch row owned by this lane (C-layout col)
  const int hh   = lane >> 5;       // k-half for A/B operands; +4 feat offset in C/D
  const int row0 = blockIdx.x * BT;
  const int cb   = wv*32 + hh*4;    // lane feature base; +8*g2 per acc group
  const int yrow = l31*YP + cb;     // LDS elem offset for this lane's stage writes

  // ---- prologue staging ----
  #pragma unroll
  for (int it = 0; it < 2; ++it){
    int idx = tid + it*512;                 // 32 rows * 32 float4
    int r = idx >> 5, c4 = idx & 31;
    float4 v = ((const float4*)inputs)[(size_t)(row0 + r)*(ID/4) + c4];
    f16x4 t = {(_Float16)v.x, (_Float16)v.y, (_Float16)v.z, (_Float16)v.w};
    *(f16x4*)(xl + r*XP + c4*4) = t;
  }
  if (tid < HD){ b1l[tid] = b1[tid]; b2l[tid] = b2[tid]; }
  bsl[tid]       = b_ih[tid]       + b_hh[tid];
  bsl[tid + 512] = b_ih[tid + 512] + b_hh[tid + 512];
  if (tid < BT) dtl[tid] = ts[row0 + tid] * (1.0f/NSTEP);

  // ---- W1, W2 strips held in VGPRs for the whole RK45 loop ----
  f16x8 W1f[16], W2f[16];
  {
    const _Float16* w1p = W1h + (size_t)(wv*32 + l31)*HD + hh*8;
    const _Float16* w2p = W2h + (size_t)(wv*32 + l31)*HD + hh*8;
    #pragma unroll
    for (int kt = 0; kt < 16; ++kt){
      W1f[kt] = *(const f16x8*)(w1p + kt*16);
      W2f[kt] = *(const f16x8*)(w2p + kt*16);
    }
  }

  // ---- master h (fp32 regs) + initial y = h0 ----
  f32x4 h4[4];
  #pragma unroll
  for (int g2 = 0; g2 < 4; ++g2){
    f32x4 hv = *(const f32x4*)(h0 + (size_t)(row0 + l31)*HD + cb + 8*g2);
    h4[g2] = hv;
    f16x4 t = {(_Float16)hv[0], (_Float16)hv[1], (_Float16)hv[2], (_Float16)hv[3]};
    *(f16x4*)(yl + yrow + 8*g2) = t;
  }
  __syncthreads();
  const float dtv = dtl[l31];

  // GEMM: acc(feat=32wv strip, batch=all 32) += Wregs * act ; act read from LDS only
  auto gemm16 = [&](const f16x8 (&Wf)[16], const _Float16* __restrict__ act)->f32x16{
    f32x16 a = {};
    const _Float16* bp = act + l31*YP + hh*8;
    #pragma unroll
    for (int kt = 0; kt < 16; ++kt){
      f16x8 Bf = *(const f16x8*)(bp + kt*16);
      a = __builtin_amdgcn_mfma_f32_32x32x16_f16(Wf[kt], Bf, a, 0, 0, 0);
    }
    return a;
  };

  // phase1: u = tanh(W1 y + b1) -> ul
  auto phase1 = [&](){
    f32x16 a = gemm16(W1f, yl);
    #pragma unroll
    for (int g2 = 0; g2 < 4; ++g2){
      f32x4 bv = *(const f32x4*)(b1l + cb + 8*g2);
      f16x4 uv;
      #pragma unroll
      for (int r3 = 0; r3 < 4; ++r3)
        uv[r3] = (_Float16)fast_tanh(a[g2*4 + r3] + bv[r3]);
      *(f16x4*)(ul + yrow + 8*g2) = uv;
    }
    __syncthreads();
  };

  #define STAGE(SIDX, YEXPR)                                              \
    phase1();                                                             \
    { f32x16 a2 = gemm16(W2f, ul);                                        \
      _Pragma("unroll")                                                   \
      for (int g2 = 0; g2 < 4; ++g2){                                     \
        f32x4 bv = *(const f32x4*)(b2l + cb + 8*g2);                      \
        f16x4 yv;                                                         \
        _Pragma("unroll")                                                 \
        for (int r3 = 0; r3 < 4; ++r3){                                   \
          const int r = g2*4 + r3; const int pk = r>>1; const int hw = r&1;\
          float kd = dtv*(a2[r] + bv[r3]);                                \
          if (SIDX < 5) kpk[SIDX][pk][hw] = (_Float16)kd;                 \
          yv[r3] = (_Float16)(YEXPR);                                     \
        }                                                                 \
        *(f16x4*)(yl + yrow + 8*g2) = yv;                                 \
      }                                                                   \
    }                                                                     \
    __syncthreads();

  // ================= RK45 (Dormand-Prince) =================
  #pragma unroll 1
  for (int step = 0; step < NSTEP; ++step){
    f16x2 kpk[5][8];   // dt-scaled slopes k1..k5, f16-packed, 40 VGPR

    STAGE(0, h4[g2][r3] + 0.2f*kd)
    STAGE(1, h4[g2][r3] + 0.075f*KP(0) + 0.225f*kd)
    STAGE(2, h4[g2][r3] + (44.0f/45.0f)*KP(0) + (-56.0f/15.0f)*KP(1)
                        + (32.0f/9.0f)*kd)
    STAGE(3, h4[g2][r3] + (19372.0f/6561.0f)*KP(0) + (-25360.0f/2187.0f)*KP(1)
                        + (64448.0f/6561.0f)*KP(2) + (-212.0f/729.0f)*kd)
    STAGE(4, h4[g2][r3] + (9017.0f/3168.0f)*KP(0) + (-355.0f/33.0f)*KP(1)
                        + (46732.0f/5247.0f)*KP(2) + (49.0f/176.0f)*KP(3)
                        + (-5103.0f/18656.0f)*kd)
    // final stage: update master h, write y = h (next step / LSTM h-in)
    phase1();
    { f32x16 a2 = gemm16(W2f, ul);
      #pragma unroll
      for (int g2 = 0; g2 < 4; ++g2){
        f32x4 bv = *(const f32x4*)(b2l + cb + 8*g2);
        f16x4 yv;
        #pragma unroll
        for (int r3 = 0; r3 < 4; ++r3){
          const int r = g2*4 + r3; const int pk = r>>1; const int hw = r&1;
          float kd = dtv*(a2[r] + bv[r3]);
          float hn = h4[g2][r3] + (35.0f/384.0f)*KP(0) + (500.0f/1113.0f)*KP(2)
                   + (125.0f/192.0f)*KP(3) + (-2187.0f/6784.0f)*KP(4)
                   + (11.0f/84.0f)*kd;
          h4[g2][r3] = hn;
          yv[r3] = (_Float16)hn;
        }
        *(f16x4*)(yl + yrow + 8*g2) = yv;
      }
    }
    __syncthreads();
  }

  // ================= two weight-shared LSTM cells =================
  // x-part of the gates is identical for both cells: compute once.
  f32x16 agx[4] = {};
  {
    const _Float16* bp = xl + l31*XP + hh*8;
    #pragma unroll 2
    for (int kt = 0; kt < 8; ++kt){
      f16x8 Bf = *(const f16x8*)(bp + kt*16);
      #pragma unroll
      for (int g = 0; g < 4; ++g){
        f16x8 Af = *(const f16x8*)(Wihh + (size_t)(g*HD + wv*32 + l31)*ID + kt*16 + hh*8);
        agx[g] = __builtin_amdgcn_mfma_f32_32x32x16_f16(Af, Bf, agx[g], 0, 0, 0);
      }
    }
  }
  f32x4 c4[4];
  #pragma unroll
  for (int g2 = 0; g2 < 4; ++g2)
    c4[g2] = *(const f32x4*)(c0 + (size_t)(row0 + l31)*HD + cb + 8*g2);

  #pragma unroll 1
  for (int cell = 0; cell < 2; ++cell){
    f32x16 ag[4];
    #pragma unroll
    for (int g = 0; g < 4; ++g) ag[g] = agx[g];
    const _Float16* hsrc = (cell == 0) ? yl : ul;
    const _Float16* bp = hsrc + l31*YP + hh*8;
    #pragma unroll 2
    for (int kt = 0; kt < 16; ++kt){
      f16x8 Bf = *(const f16x8*)(bp + kt*16);
      #pragma unroll
      for (int g = 0; g < 4; ++g){
        f16x8 Af = *(const f16x8*)(Whhh + (size_t)(g*HD + wv*32 + l31)*HD + kt*16 + hh*8);
        ag[g] = __builtin_amdgcn_mfma_f32_32x32x16_f16(Af, Bf, ag[g], 0, 0, 0);
      }
    }
    #pragma unroll
    for (int g2 = 0; g2 < 4; ++g2){
      f32x4 bi = *(const f32x4*)(bsl + 0*HD + cb + 8*g2);
      f32x4 bf = *(const f32x4*)(bsl + 1*HD + cb + 8*g2);
      f32x4 bg = *(const f32x4*)(bsl + 2*HD + cb + 8*g2);
      f32x4 bo = *(const f32x4*)(bsl + 3*HD + cb + 8*g2);
      f16x4 hv; f32x4 ho, co;
      #pragma unroll
      for (int r3 = 0; r3 < 4; ++r3){
        const int r = g2*4 + r3;
        float iv = fast_sigmoid(ag[0][r] + bi[r3]);
        float fv = fast_sigmoid(ag[1][r] + bf[r3]);
        float gv = fast_tanh   (ag[2][r] + bg[r3]);
        float ov = fast_sigmoid(ag[3][r] + bo[r3]);
        float cn = fv*c4[g2][r3] + iv*gv;
        c4[g2][r3] = cn;
        float hn = ov*fast_tanh(cn);
        hv[r3] = (_Float16)hn; ho[r3] = hn; co[r3] = cn;
      }
      if (cell == 0){
        *(f16x4*)(ul + yrow + 8*g2) = hv;          // h1 -> cell2 input
      } else {
        size_t o = (size_t)(row0 + l31)*HD + cb + 8*g2;
        *(f32x4*)(out + o) = ho;                   // h2
        *(f32x4*)(out + (size_t)B_TOT*HD + o) = co;// c2
      }
    }
    if (cell == 0) __syncthreads();
  }
}

extern "C" void kernel_launch(void* const* d_in, const int* in_sizes, int n_in,
                              void* d_out, int out_size, void* d_ws, size_t ws_size,
                              hipStream_t stream) {
  (void)in_sizes; (void)n_in; (void)out_size; (void)ws_size;
  const float* inputs = (const float*)d_in[0];
  const float* h0     = (const float*)d_in[1];
  const float* c0     = (const float*)d_in[2];
  const float* ts     = (const float*)d_in[3];
  const float* W_ih   = (const float*)d_in[4];
  const float* W_hh   = (const float*)d_in[5];
  const float* b_ih   = (const float*)d_in[6];
  const float* b_hh   = (const float*)d_in[7];
  const float* W1     = (const float*)d_in[8];
  const float* b1     = (const float*)d_in[9];
  const float* W2     = (const float*)d_in[10];
  const float* b2     = (const float*)d_in[11];
  float* out = (float*)d_out;

  _Float16* wsh  = (_Float16*)d_ws;
  _Float16* W1h  = wsh;             // 65536
  _Float16* W2h  = wsh + 65536;     // 65536
  _Float16* Wihh = wsh + 131072;    // 131072
  _Float16* Whhh = wsh + 262144;    // 262144  (total 1 MB)

  cvt_f32_f16<<<64,  256, 0, stream>>>(W1,   W1h,  16384);
  cvt_f32_f16<<<64,  256, 0, stream>>>(W2,   W2h,  16384);
  cvt_f32_f16<<<128, 256, 0, stream>>>(W_ih, Wihh, 32768);
  cvt_f32_f16<<<256, 256, 0, stream>>>(W_hh, Whhh, 65536);

  ode_lstm<<<B_TOT/BT, 512, 0, stream>>>(inputs, h0, c0, ts, b_ih, b_hh, b1, b2,
                                         W1h, W2h, Wihh, Whhh, out);
}